// Round 4
// baseline (859.767 us; speedup 1.0000x reference)
//
#include <hip/hip_runtime.h>

#define IN_CH 1024
#define INTER 512
#define NEXP  128
#define TPE   512

typedef __bf16 bf16x8  __attribute__((ext_vector_type(8)));
typedef float  f32x4   __attribute__((ext_vector_type(4)));

// ---------------- Kernel A: h = silu(x@w1^T + b1) * (x@w3^T + b3) ------------
// 512 threads / 8 waves (4x2), BM=BN=128, BK=32, double-buffered LDS (48 KB
// -> 2 blocks/CU), one raw s_barrier per K-step, loads(t+2) in flight across
// the barrier. Staging: 1x16B chunk per tile per thread (2 float4 + cvt +
// ds_write_b128), XOR swizzle chunk^(row&3).
__global__ __launch_bounds__(512, 4) void moe_h_kernel(
    const float* __restrict__ x, const int* __restrict__ idxs,
    const float* __restrict__ w1w, const float* __restrict__ w1b,
    const float* __restrict__ w3w, const float* __restrict__ w3b,
    __bf16* __restrict__ hbuf)
{
  __shared__ __align__(16) ushort sA [2][128*32];
  __shared__ __align__(16) ushort sB1[2][128*32];
  __shared__ __align__(16) ushort sB3[2][128*32];   // 48 KB total

  // XCD swizzle: 2048 blocks, 256/XCD -> each expert's 16 tiles on one XCD
  const int blk = (blockIdx.x & 7) * (NEXP*16/8) + (blockIdx.x >> 3);
  const int e   = blk >> 4;
  const int tl  = blk & 15;
  const int tm  = tl >> 2, tn = tl & 3;

  const int tid  = threadIdx.x;
  const int lane = tid & 63;
  const int wid  = tid >> 6;       // 0..7
  const int wm   = wid >> 1;       // 0..3 -> 32-row slice
  const int wn   = wid & 1;        // 0..1 -> 64-col slice

  // staging: thread owns (row, chunk c) ; chunk = 8 consecutive k-elems (16B bf16)
  const int row = tid >> 2;        // 0..127
  const int c   = tid & 3;         // 0..3
  const int sro = row*32 + ((c ^ (row&3))<<3);   // swizzled LDS offset (ushorts)

  const int tok = idxs[e*TPE + tm*128 + row];
  const float* ap  = x   + (size_t)tok*IN_CH + (c<<3);
  const float* b1p = w1w + ((size_t)e*INTER + tn*128 + row)*IN_CH + (c<<3);
  const float* b3p = w3w + ((size_t)e*INTER + tn*128 + row)*IN_CH + (c<<3);

  f32x4 acc1[2][4], acc3[2][4];
#pragma unroll
  for (int a = 0; a < 2; ++a)
#pragma unroll
    for (int b = 0; b < 4; ++b) {
      acc1[a][b] = (f32x4){0.f,0.f,0.f,0.f};
      acc3[a][b] = (f32x4){0.f,0.f,0.f,0.f};
    }

  float4 xa, xb, w1a, w1b_, w3a, w3b_;

  auto loads = [&](int kof) {
    xa   = *(const float4*)(ap  + kof);
    xb   = *(const float4*)(ap  + kof + 4);
    w1a  = *(const float4*)(b1p + kof);
    w1b_ = *(const float4*)(b1p + kof + 4);
    w3a  = *(const float4*)(b3p + kof);
    w3b_ = *(const float4*)(b3p + kof + 4);
  };
  auto cvt8 = [](const float4& lo, const float4& hi) {
    bf16x8 r;
    r[0]=(__bf16)lo.x; r[1]=(__bf16)lo.y; r[2]=(__bf16)lo.z; r[3]=(__bf16)lo.w;
    r[4]=(__bf16)hi.x; r[5]=(__bf16)hi.y; r[6]=(__bf16)hi.z; r[7]=(__bf16)hi.w;
    return r;
  };
  auto stores = [&](int buf) {
    *(bf16x8*)&sA [buf][sro] = cvt8(xa,  xb);
    *(bf16x8*)&sB1[buf][sro] = cvt8(w1a, w1b_);
    *(bf16x8*)&sB3[buf][sro] = cvt8(w3a, w3b_);
  };
  auto mfma_tile = [&](int buf) {
    bf16x8 af[2], bq[4], bt[4];
    const int k8 = lane>>4;
#pragma unroll
    for (int mi = 0; mi < 2; ++mi) {
      const int r = wm*32 + mi*16 + (lane&15);
      af[mi] = *(const bf16x8*)&sA[buf][r*32 + ((k8 ^ (r&3))<<3)];
    }
#pragma unroll
    for (int ni = 0; ni < 4; ++ni) {
      const int r   = wn*64 + ni*16 + (lane&15);
      const int off = r*32 + ((k8 ^ (r&3))<<3);
      bq[ni] = *(const bf16x8*)&sB1[buf][off];
      bt[ni] = *(const bf16x8*)&sB3[buf][off];
    }
#pragma unroll
    for (int mi = 0; mi < 2; ++mi)
#pragma unroll
      for (int ni = 0; ni < 4; ++ni) {
        acc1[mi][ni] = __builtin_amdgcn_mfma_f32_16x16x32_bf16(af[mi], bq[ni], acc1[mi][ni], 0, 0, 0);
        acc3[mi][ni] = __builtin_amdgcn_mfma_f32_16x16x32_bf16(af[mi], bt[ni], acc3[mi][ni], 0, 0, 0);
      }
  };

  loads(0);
  stores(0);
  loads(32);
  asm volatile("s_waitcnt lgkmcnt(0)" ::: "memory");
  __builtin_amdgcn_s_barrier();

  int cur = 0;
  const int NT = IN_CH/32;
  for (int kt = 0; kt < NT; ++kt) {
    if (kt < NT - 1) {
      stores(cur ^ 1);                         // waits vmcnt for regs(t+1) here
      if (kt < NT - 2) loads((kt+2)*32);       // t+2 rides across the barrier
    }
    __builtin_amdgcn_s_setprio(1);
    mfma_tile(cur);
    __builtin_amdgcn_s_setprio(0);
    asm volatile("s_waitcnt lgkmcnt(0)" ::: "memory");
    __builtin_amdgcn_s_barrier();
    cur ^= 1;
  }

  // epilogue: bias + SwiGLU, store bf16 h tile
  const int rowbase = tm*128 + wm*32;
  const int colbase = tn*128 + wn*64;
#pragma unroll
  for (int ni = 0; ni < 4; ++ni) {
    const int fc = colbase + ni*16 + (lane&15);
    const float b1v = w1b[e*INTER + fc];
    const float b3v = w3b[e*INTER + fc];
#pragma unroll
    for (int mi = 0; mi < 2; ++mi) {
#pragma unroll
      for (int j = 0; j < 4; ++j) {
        const int rl = rowbase + mi*16 + ((lane>>4)<<2) + j;
        const float h1 = acc1[mi][ni][j] + b1v;
        const float h3 = acc3[mi][ni][j] + b3v;
        const float s  = h1 / (1.0f + __expf(-h1));
        hbuf[((size_t)e*TPE + rl)*INTER + fc] = (__bf16)(s * h3);
      }
    }
  }
}

// ---------------- Kernel B: out = h @ w2^T + b2, scattered via idxs ----------
// Same structure; BK=32 -> 32 KB LDS -> 3+ blocks/CU. K = 512 (16 steps).
__global__ __launch_bounds__(512, 4) void moe_out_kernel(
    const __bf16* __restrict__ hbuf, const float* __restrict__ w2w,
    const float* __restrict__ w2b, const int* __restrict__ idxs,
    float* __restrict__ out)
{
  __shared__ __align__(16) ushort sA[2][128*32];
  __shared__ __align__(16) ushort sB[2][128*32];   // 32 KB total

  const int blk = (blockIdx.x & 7) * (NEXP*32/8) + (blockIdx.x >> 3);
  const int e   = blk >> 5;
  const int tl  = blk & 31;
  const int tm  = tl >> 3, tn = tl & 7;

  const int tid  = threadIdx.x;
  const int lane = tid & 63;
  const int wid  = tid >> 6;
  const int wm   = wid >> 1;       // 0..3
  const int wn   = wid & 1;        // 0..1

  const int row = tid >> 2;        // 0..127
  const int c   = tid & 3;         // 0..3
  const int sro = row*32 + ((c ^ (row&3))<<3);

  // A (h, already bf16): one 16B chunk per thread
  const __bf16* ap = hbuf + ((size_t)e*TPE + tm*128 + row)*INTER + (c<<3);
  // B (w2, fp32 -> bf16)
  const float*  bp = w2w + ((size_t)e*IN_CH + tn*128 + row)*INTER + (c<<3);

  f32x4 acc[2][4];
#pragma unroll
  for (int a = 0; a < 2; ++a)
#pragma unroll
    for (int b = 0; b < 4; ++b) acc[a][b] = (f32x4){0.f,0.f,0.f,0.f};

  uint4  hv;
  float4 wa, wb;

  auto loads = [&](int kof) {
    hv = *(const uint4*)(ap + kof);
    wa = *(const float4*)(bp + kof);
    wb = *(const float4*)(bp + kof + 4);
  };
  auto stores = [&](int buf) {
    *(uint4*)&sA[buf][sro] = hv;
    bf16x8 r;
    r[0]=(__bf16)wa.x; r[1]=(__bf16)wa.y; r[2]=(__bf16)wa.z; r[3]=(__bf16)wa.w;
    r[4]=(__bf16)wb.x; r[5]=(__bf16)wb.y; r[6]=(__bf16)wb.z; r[7]=(__bf16)wb.w;
    *(bf16x8*)&sB[buf][sro] = r;
  };
  auto mfma_tile = [&](int buf) {
    bf16x8 af[2], bf[4];
    const int k8 = lane>>4;
#pragma unroll
    for (int mi = 0; mi < 2; ++mi) {
      const int r = wm*32 + mi*16 + (lane&15);
      af[mi] = *(const bf16x8*)&sA[buf][r*32 + ((k8 ^ (r&3))<<3)];
    }
#pragma unroll
    for (int ni = 0; ni < 4; ++ni) {
      const int r = wn*64 + ni*16 + (lane&15);
      bf[ni] = *(const bf16x8*)&sB[buf][r*32 + ((k8 ^ (r&3))<<3)];
    }
#pragma unroll
    for (int mi = 0; mi < 2; ++mi)
#pragma unroll
      for (int ni = 0; ni < 4; ++ni)
        acc[mi][ni] = __builtin_amdgcn_mfma_f32_16x16x32_bf16(af[mi], bf[ni], acc[mi][ni], 0, 0, 0);
  };

  loads(0);
  stores(0);
  loads(32);
  asm volatile("s_waitcnt lgkmcnt(0)" ::: "memory");
  __builtin_amdgcn_s_barrier();

  int cur = 0;
  const int NT = INTER/32;
  for (int kt = 0; kt < NT; ++kt) {
    if (kt < NT - 1) {
      stores(cur ^ 1);
      if (kt < NT - 2) loads((kt+2)*32);
    }
    __builtin_amdgcn_s_setprio(1);
    mfma_tile(cur);
    __builtin_amdgcn_s_setprio(0);
    asm volatile("s_waitcnt lgkmcnt(0)" ::: "memory");
    __builtin_amdgcn_s_barrier();
    cur ^= 1;
  }

  // epilogue: bias + scatter to original token positions (fp32)
  const int rowbase = tm*128 + wm*32;
  const int colbase = tn*128 + wn*64;
  float b2v[4];
#pragma unroll
  for (int ni = 0; ni < 4; ++ni)
    b2v[ni] = w2b[e*IN_CH + colbase + ni*16 + (lane&15)];
#pragma unroll
  for (int mi = 0; mi < 2; ++mi) {
#pragma unroll
    for (int j = 0; j < 4; ++j) {
      const int rl  = rowbase + mi*16 + ((lane>>4)<<2) + j;
      const int tok = idxs[e*TPE + rl];
      float* orow = out + (size_t)tok*IN_CH;
#pragma unroll
      for (int ni = 0; ni < 4; ++ni)
        orow[colbase + ni*16 + (lane&15)] = acc[mi][ni][j] + b2v[ni];
    }
  }
}

extern "C" void kernel_launch(void* const* d_in, const int* in_sizes, int n_in,
                              void* d_out, int out_size, void* d_ws, size_t ws_size,
                              hipStream_t stream) {
  const float* x    = (const float*)d_in[0];
  const int*   idxs = (const int*)d_in[1];
  const float* w1w  = (const float*)d_in[2];
  const float* w1b  = (const float*)d_in[3];
  const float* w2w  = (const float*)d_in[4];
  const float* w2b  = (const float*)d_in[5];
  const float* w3w  = (const float*)d_in[6];
  const float* w3b  = (const float*)d_in[7];
  float*  out  = (float*)d_out;
  __bf16* hbuf = (__bf16*)d_ws;   // 128*512*512 bf16 = 64 MB intermediate

  moe_h_kernel<<<dim3(NEXP*16), dim3(512), 0, stream>>>(x, idxs, w1w, w1b, w3w, w3b, hbuf);
  moe_out_kernel<<<dim3(NEXP*32), dim3(512), 0, stream>>>(hbuf, w2w, w2b, idxs, out);
}

// Round 5
// 527.560 us; speedup vs baseline: 1.6297x; 1.6297x over previous
//
#include <hip/hip_runtime.h>

#define IN_CH 1024
#define INTER 512
#define NEXP  128
#define TPE   512

typedef __bf16 bf16x8  __attribute__((ext_vector_type(8)));
typedef float  f32x4   __attribute__((ext_vector_type(4)));

// Phase scaffolding (m201 8-phase rhythm): barrier orders issue; lgkmcnt(0)
// drains this wave's ds ops; sched_barrier stops MFMA hoisting (rule #18);
// setprio keeps matrix pipe fed (T5).
#define PHASE_SYNC() do { \
  __builtin_amdgcn_s_barrier(); \
  asm volatile("s_waitcnt lgkmcnt(0)" ::: "memory"); \
  __builtin_amdgcn_sched_barrier(0); \
  __builtin_amdgcn_s_setprio(1); } while (0)
#define PHASE_END() do { \
  __builtin_amdgcn_s_setprio(0); \
  __builtin_amdgcn_s_barrier(); } while (0)

// ---------------- Kernel A: h = silu(x@w1^T + b1) * (x@w3^T + b3) ------------
// 512 threads / 8 waves (4x2), BM=BN=128, BK=64, dbuf LDS (96 KB, 1 blk/CU).
// 4 phases per K-tile: (ks, N-half) quadrants; stage W(t+1) in p2, L(t+2) in p3.
__global__ __launch_bounds__(512) void moe_h_kernel(
    const float* __restrict__ x, const int* __restrict__ idxs,
    const float* __restrict__ w1w, const float* __restrict__ w1b,
    const float* __restrict__ w3w, const float* __restrict__ w3b,
    __bf16* __restrict__ hbuf)
{
  __shared__ __align__(16) ushort sA [2][128*64];
  __shared__ __align__(16) ushort sB1[2][128*64];
  __shared__ __align__(16) ushort sB3[2][128*64];

  const int blk = (blockIdx.x & 7) * (NEXP*16/8) + (blockIdx.x >> 3);
  const int e   = blk >> 4;
  const int tl  = blk & 15;
  const int tm  = tl >> 2, tn = tl & 3;

  const int tid  = threadIdx.x;
  const int lane = tid & 63;
  const int wid  = tid >> 6;
  const int wm   = wid >> 1;       // 0..3 -> 32-row slice
  const int wn   = wid & 1;        // 0..1 -> 64-col slice

  const int r0 = tid >> 4;   // 0..31
  const int c4 = tid & 15;   // 0..15

  const float* aptr[4];
#pragma unroll
  for (int i = 0; i < 4; ++i) {
    const int tok = idxs[e*TPE + tm*128 + r0 + 32*i];
    aptr[i] = x + (size_t)tok*IN_CH + (c4<<2);
  }
  const float* b1p = w1w + ((size_t)e*INTER + tn*128 + r0)*IN_CH + (c4<<2);
  const float* b3p = w3w + ((size_t)e*INTER + tn*128 + r0)*IN_CH + (c4<<2);

  const int swz = ((((c4>>1) ^ (r0&7))<<3) | ((c4&1)<<2));

  f32x4 acc1[2][4], acc3[2][4];
#pragma unroll
  for (int a = 0; a < 2; ++a)
#pragma unroll
    for (int b = 0; b < 4; ++b) {
      acc1[a][b] = (f32x4){0.f,0.f,0.f,0.f};
      acc3[a][b] = (f32x4){0.f,0.f,0.f,0.f};
    }

  float4 xv[4], v1[4], v3[4];

  auto loads = [&](int kof) {
#pragma unroll
    for (int i = 0; i < 4; ++i) {
      xv[i] = *(const float4*)(aptr[i] + kof);
      v1[i] = *(const float4*)(b1p + (size_t)(32*i)*IN_CH + kof);
      v3[i] = *(const float4*)(b3p + (size_t)(32*i)*IN_CH + kof);
    }
  };
  auto stores = [&](int buf) {
#pragma unroll
    for (int i = 0; i < 4; ++i) {
      const int ro = (r0 + 32*i)*64 + swz;
      typedef __bf16 bf16x4v __attribute__((ext_vector_type(4)));
      bf16x4v a, b, c;
      a[0]=(__bf16)xv[i].x; a[1]=(__bf16)xv[i].y; a[2]=(__bf16)xv[i].z; a[3]=(__bf16)xv[i].w;
      b[0]=(__bf16)v1[i].x; b[1]=(__bf16)v1[i].y; b[2]=(__bf16)v1[i].z; b[3]=(__bf16)v1[i].w;
      c[0]=(__bf16)v3[i].x; c[1]=(__bf16)v3[i].y; c[2]=(__bf16)v3[i].z; c[3]=(__bf16)v3[i].w;
      *(bf16x4v*)&sA [buf][ro] = a;
      *(bf16x4v*)&sB1[buf][ro] = b;
      *(bf16x4v*)&sB3[buf][ro] = c;
    }
  };
  auto rdA = [&](int buf, int ks, bf16x8 af[2]) {
    const int k8 = (ks<<2) + (lane>>4);
#pragma unroll
    for (int mi = 0; mi < 2; ++mi) {
      const int r = wm*32 + mi*16 + (lane&15);
      af[mi] = *(const bf16x8*)&sA[buf][r*64 + ((k8 ^ (r&7))<<3)];
    }
  };
  auto rdB = [&](int buf, int ks, int nh, bf16x8 bq[2], bf16x8 bt[2]) {
    const int k8 = (ks<<2) + (lane>>4);
#pragma unroll
    for (int nl = 0; nl < 2; ++nl) {
      const int r   = wn*64 + (nh*2 + nl)*16 + (lane&15);
      const int off = r*64 + ((k8 ^ (r&7))<<3);
      bq[nl] = *(const bf16x8*)&sB1[buf][off];
      bt[nl] = *(const bf16x8*)&sB3[buf][off];
    }
  };

  // prologue
  loads(0);
  stores(0);
  loads(64);
  asm volatile("s_waitcnt lgkmcnt(0)" ::: "memory");
  __builtin_amdgcn_s_barrier();

  int cur = 0;
  const int NT = IN_CH/64;
  for (int kt = 0; kt < NT; ++kt) {
    bf16x8 af[2], bq[2], bt[2];

    // phase 0: ks=0, N-half 0
    rdA(cur, 0, af);
    rdB(cur, 0, 0, bq, bt);
    PHASE_SYNC();
#pragma unroll
    for (int mi = 0; mi < 2; ++mi)
#pragma unroll
      for (int nl = 0; nl < 2; ++nl) {
        acc1[mi][nl] = __builtin_amdgcn_mfma_f32_16x16x32_bf16(af[mi], bq[nl], acc1[mi][nl], 0, 0, 0);
        acc3[mi][nl] = __builtin_amdgcn_mfma_f32_16x16x32_bf16(af[mi], bt[nl], acc3[mi][nl], 0, 0, 0);
      }
    PHASE_END();

    // phase 1: ks=0, N-half 1 (A frags reused)
    rdB(cur, 0, 1, bq, bt);
    PHASE_SYNC();
#pragma unroll
    for (int mi = 0; mi < 2; ++mi)
#pragma unroll
      for (int nl = 0; nl < 2; ++nl) {
        acc1[mi][2+nl] = __builtin_amdgcn_mfma_f32_16x16x32_bf16(af[mi], bq[nl], acc1[mi][2+nl], 0, 0, 0);
        acc3[mi][2+nl] = __builtin_amdgcn_mfma_f32_16x16x32_bf16(af[mi], bt[nl], acc3[mi][2+nl], 0, 0, 0);
      }
    PHASE_END();

    // phase 2: ks=1, N-half 0 + cvt/ds_write of tile t+1
    rdA(cur, 1, af);
    rdB(cur, 1, 0, bq, bt);
    if (kt < NT - 1) stores(cur ^ 1);
    PHASE_SYNC();
#pragma unroll
    for (int mi = 0; mi < 2; ++mi)
#pragma unroll
      for (int nl = 0; nl < 2; ++nl) {
        acc1[mi][nl] = __builtin_amdgcn_mfma_f32_16x16x32_bf16(af[mi], bq[nl], acc1[mi][nl], 0, 0, 0);
        acc3[mi][nl] = __builtin_amdgcn_mfma_f32_16x16x32_bf16(af[mi], bt[nl], acc3[mi][nl], 0, 0, 0);
      }
    PHASE_END();

    // phase 3: ks=1, N-half 1 + issue loads of tile t+2
    rdB(cur, 1, 1, bq, bt);
    if (kt < NT - 2) loads((kt+2)*64);
    PHASE_SYNC();
#pragma unroll
    for (int mi = 0; mi < 2; ++mi)
#pragma unroll
      for (int nl = 0; nl < 2; ++nl) {
        acc1[mi][2+nl] = __builtin_amdgcn_mfma_f32_16x16x32_bf16(af[mi], bq[nl], acc1[mi][2+nl], 0, 0, 0);
        acc3[mi][2+nl] = __builtin_amdgcn_mfma_f32_16x16x32_bf16(af[mi], bt[nl], acc3[mi][2+nl], 0, 0, 0);
      }
    PHASE_END();

    cur ^= 1;
  }

  // epilogue: bias + SwiGLU, store bf16 h tile
  const int rowbase = tm*128 + wm*32;
  const int colbase = tn*128 + wn*64;
#pragma unroll
  for (int ni = 0; ni < 4; ++ni) {
    const int fc = colbase + ni*16 + (lane&15);
    const float b1v = w1b[e*INTER + fc];
    const float b3v = w3b[e*INTER + fc];
#pragma unroll
    for (int mi = 0; mi < 2; ++mi) {
#pragma unroll
      for (int j = 0; j < 4; ++j) {
        const int rl = rowbase + mi*16 + ((lane>>4)<<2) + j;
        const float h1 = acc1[mi][ni][j] + b1v;
        const float h3 = acc3[mi][ni][j] + b3v;
        const float s  = h1 / (1.0f + __expf(-h1));
        hbuf[((size_t)e*TPE + rl)*INTER + fc] = (__bf16)(s * h3);
      }
    }
  }
}

// ---------------- Kernel B: out = h @ w2^T + b2, scattered via idxs ----------
// Same structure; 64 KB LDS -> 2 blocks/CU; 2 phases per K-tile (ks halves).
__global__ __launch_bounds__(512) void moe_out_kernel(
    const __bf16* __restrict__ hbuf, const float* __restrict__ w2w,
    const float* __restrict__ w2b, const int* __restrict__ idxs,
    float* __restrict__ out)
{
  __shared__ __align__(16) ushort sA[2][128*64];
  __shared__ __align__(16) ushort sB[2][128*64];

  const int blk = (blockIdx.x & 7) * (NEXP*32/8) + (blockIdx.x >> 3);
  const int e   = blk >> 5;
  const int tl  = blk & 31;
  const int tm  = tl >> 3, tn = tl & 7;

  const int tid  = threadIdx.x;
  const int lane = tid & 63;
  const int wid  = tid >> 6;
  const int wm   = wid >> 1;       // 0..3
  const int wn   = wid & 1;        // 0..1

  const int rA   = tid >> 3;          // 0..63
  const int c8   = tid & 7;           // 0..7
  const int swzA = ((c8 ^ (rA&7))<<3);
  const __bf16* ap = hbuf + ((size_t)e*TPE + tm*128 + rA)*INTER + (c8<<3);

  const int r0   = tid >> 4;          // 0..31
  const int c4   = tid & 15;
  const int swzB = ((((c4>>1) ^ (r0&7))<<3) | ((c4&1)<<2));
  const float* bp = w2w + ((size_t)e*IN_CH + tn*128 + r0)*INTER + (c4<<2);

  f32x4 acc[2][4];
#pragma unroll
  for (int a = 0; a < 2; ++a)
#pragma unroll
    for (int b = 0; b < 4; ++b) acc[a][b] = (f32x4){0.f,0.f,0.f,0.f};

  uint4  hv[2];
  float4 wv[4];

  auto loads = [&](int kof) {
#pragma unroll
    for (int i = 0; i < 2; ++i)
      hv[i] = *(const uint4*)(ap + (size_t)(64*i)*INTER + kof);
#pragma unroll
    for (int i = 0; i < 4; ++i)
      wv[i] = *(const float4*)(bp + (size_t)(32*i)*INTER + kof);
  };
  auto stores = [&](int buf) {
#pragma unroll
    for (int i = 0; i < 2; ++i)
      *(uint4*)&sA[buf][(rA + 64*i)*64 + swzA] = hv[i];
#pragma unroll
    for (int i = 0; i < 4; ++i) {
      typedef __bf16 bf16x4v __attribute__((ext_vector_type(4)));
      bf16x4v b;
      b[0]=(__bf16)wv[i].x; b[1]=(__bf16)wv[i].y; b[2]=(__bf16)wv[i].z; b[3]=(__bf16)wv[i].w;
      *(bf16x4v*)&sB[buf][(r0 + 32*i)*64 + swzB] = b;
    }
  };
  auto rdA = [&](int buf, int ks, bf16x8 af[2]) {
    const int k8 = (ks<<2) + (lane>>4);
#pragma unroll
    for (int mi = 0; mi < 2; ++mi) {
      const int r = wm*32 + mi*16 + (lane&15);
      af[mi] = *(const bf16x8*)&sA[buf][r*64 + ((k8 ^ (r&7))<<3)];
    }
  };
  auto rdB = [&](int buf, int ks, bf16x8 bfr[4]) {
    const int k8 = (ks<<2) + (lane>>4);
#pragma unroll
    for (int ni = 0; ni < 4; ++ni) {
      const int r = wn*64 + ni*16 + (lane&15);
      bfr[ni] = *(const bf16x8*)&sB[buf][r*64 + ((k8 ^ (r&7))<<3)];
    }
  };

  loads(0);
  stores(0);
  loads(64);
  asm volatile("s_waitcnt lgkmcnt(0)" ::: "memory");
  __builtin_amdgcn_s_barrier();

  int cur = 0;
  const int NT = INTER/64;
  for (int kt = 0; kt < NT; ++kt) {
    bf16x8 af[2], bfr[4];

    // phase 0: ks=0 + cvt/ds_write of tile t+1
    rdA(cur, 0, af);
    rdB(cur, 0, bfr);
    if (kt < NT - 1) stores(cur ^ 1);
    PHASE_SYNC();
#pragma unroll
    for (int mi = 0; mi < 2; ++mi)
#pragma unroll
      for (int ni = 0; ni < 4; ++ni)
        acc[mi][ni] = __builtin_amdgcn_mfma_f32_16x16x32_bf16(af[mi], bfr[ni], acc[mi][ni], 0, 0, 0);
    PHASE_END();

    // phase 1: ks=1 + issue loads of tile t+2
    rdA(cur, 1, af);
    rdB(cur, 1, bfr);
    if (kt < NT - 2) loads((kt+2)*64);
    PHASE_SYNC();
#pragma unroll
    for (int mi = 0; mi < 2; ++mi)
#pragma unroll
      for (int ni = 0; ni < 4; ++ni)
        acc[mi][ni] = __builtin_amdgcn_mfma_f32_16x16x32_bf16(af[mi], bfr[ni], acc[mi][ni], 0, 0, 0);
    PHASE_END();

    cur ^= 1;
  }

  // epilogue: bias + scatter to original token positions (fp32)
  const int rowbase = tm*128 + wm*32;
  const int colbase = tn*128 + wn*64;
  float b2v[4];
#pragma unroll
  for (int ni = 0; ni < 4; ++ni)
    b2v[ni] = w2b[e*IN_CH + colbase + ni*16 + (lane&15)];
#pragma unroll
  for (int mi = 0; mi < 2; ++mi) {
#pragma unroll
    for (int j = 0; j < 4; ++j) {
      const int rl  = rowbase + mi*16 + ((lane>>4)<<2) + j;
      const int tok = idxs[e*TPE + rl];
      float* orow = out + (size_t)tok*IN_CH;
#pragma unroll
      for (int ni = 0; ni < 4; ++ni)
        orow[colbase + ni*16 + (lane&15)] = acc[mi][ni][j] + b2v[ni];
    }
  }
}

extern "C" void kernel_launch(void* const* d_in, const int* in_sizes, int n_in,
                              void* d_out, int out_size, void* d_ws, size_t ws_size,
                              hipStream_t stream) {
  const float* x    = (const float*)d_in[0];
  const int*   idxs = (const int*)d_in[1];
  const float* w1w  = (const float*)d_in[2];
  const float* w1b  = (const float*)d_in[3];
  const float* w2w  = (const float*)d_in[4];
  const float* w2b  = (const float*)d_in[5];
  const float* w3w  = (const float*)d_in[6];
  const float* w3b  = (const float*)d_in[7];
  float*  out  = (float*)d_out;
  __bf16* hbuf = (__bf16*)d_ws;   // 128*512*512 bf16 = 64 MB intermediate

  moe_h_kernel<<<dim3(NEXP*16), dim3(512), 0, stream>>>(x, idxs, w1w, w1b, w3w, w3b, hbuf);
  moe_out_kernel<<<dim3(NEXP*32), dim3(512), 0, stream>>>(hbuf, w2w, w2b, idxs, out);
}